// Round 2
// baseline (224.408 us; speedup 1.0000x reference)
//
#include <hip/hip_runtime.h>
#include <hip/hip_bf16.h>
#include <stdint.h>

typedef __hip_bfloat16 bf16;
typedef __attribute__((ext_vector_type(8))) short bf16x8;   // 8 bf16 = 4 VGPRs (MFMA A/B frag)
typedef __attribute__((ext_vector_type(4))) float f32x4;    // MFMA C/D frag

#define B_  2
#define L_  2048
#define D_  1024
#define H_  16
#define HD_ 64
#define BH_ 32
#define L2E 1.4426950408889634f

#define DEV static __device__ __forceinline__

DEV short f2bf(float f) {
    bf16 h = __float2bfloat16(f);
    return __builtin_bit_cast(short, h);
}

DEV f32x4 mfma16(bf16x8 a, bf16x8 b, f32x4 c) {
    return __builtin_amdgcn_mfma_f32_16x16x32_bf16(a, b, c, 0, 0, 0);
}

// async global->LDS, 16B per lane; lds ptr must be wave-uniform (HW adds lane*16)
DEV void async_ld16(const void* g, void* lds_uniform) {
    __builtin_amdgcn_global_load_lds((const __attribute__((address_space(1))) void*)g,
                                     (__attribute__((address_space(3))) void*)lds_uniform,
                                     16, 0, 0);
}

// XOR-swizzled element offset inside a [rows][64] bf16 tile (128B rows).
DEV int swz(int row, int col) {
    int blk = (row << 3) + (col >> 3);
    blk ^= (row & 7);
    return (blk << 3) + (col & 7);
}

// ---------------------------------------------------------------- cast x -> bf16
__global__ __launch_bounds__(256) void k_cast_x(const float* __restrict__ x,
                                                bf16* __restrict__ xb, int n8) {
    int i = blockIdx.x * 256 + threadIdx.x;
    if (i >= n8) return;
    const float4* src = (const float4*)x + (size_t)i * 2;
    float4 a = src[0], b = src[1];
    bf16x8 v;
    v[0]=f2bf(a.x); v[1]=f2bf(a.y); v[2]=f2bf(a.z); v[3]=f2bf(a.w);
    v[4]=f2bf(b.x); v[5]=f2bf(b.y); v[6]=f2bf(b.z); v[7]=f2bf(b.w);
    *(bf16x8*)(xb + (size_t)i * 8) = v;
}

// ------------------------------------------- cast + transpose weights -> WT[n][k] bf16
__global__ __launch_bounds__(256) void k_cast_wT(const float* __restrict__ W0, const float* __restrict__ W1,
                                                 const float* __restrict__ W2, const float* __restrict__ W3,
                                                 bf16* __restrict__ WT) {
    const float* W = (blockIdx.z == 0) ? W0 : (blockIdx.z == 1) ? W1 : (blockIdx.z == 2) ? W2 : W3;
    __shared__ float tile[64][65];
    const int r0 = blockIdx.y * 64, c0 = blockIdx.x * 64;
    const int tx = threadIdx.x & 63, ty = threadIdx.x >> 6;
    #pragma unroll
    for (int i = 0; i < 16; ++i) {
        int r = ty + i * 4;
        tile[r][tx] = W[(size_t)(r0 + r) * D_ + c0 + tx];
    }
    __syncthreads();
    bf16* out = WT + (size_t)blockIdx.z * D_ * D_;
    #pragma unroll
    for (int i = 0; i < 16; ++i) {
        int n = ty + i * 4;
        out[(size_t)(c0 + n) * D_ + r0 + tx] = __float2bfloat16(tile[tx][n]);
    }
}

// ---------------------------------------------------------------- GEMM 128x128, BK=64
// C[M,N] = A[M,1024] * BT[N,1024]^T.  MODE 0: scatter bf16 into QKV regions. MODE 1: f32 out.
template <int MODE>
__global__ __launch_bounds__(256) void k_gemm(const bf16* __restrict__ A, const bf16* __restrict__ BT,
                                              void* __restrict__ C) {
    __shared__ __align__(16) bf16 As[128 * 64];
    __shared__ __align__(16) bf16 Bs[128 * 64];
    const int t = threadIdx.x;
    const int w = t >> 6, lane = t & 63;
    const int lr = lane & 15, lg = lane >> 4;
    const int wr = (w >> 1) * 64, wc = (w & 1) * 64;
    const size_t am0 = (size_t)blockIdx.y * 128;
    const size_t bn0 = (size_t)blockIdx.x * 128;

    f32x4 acc[4][4] = {};

    for (int kt = 0; kt < 1024 / 64; ++kt) {
        const int k0 = kt * 64;
        if (kt) __syncthreads();
        #pragma unroll
        for (int c = 0; c < 4; ++c) {
            int phys = c * 256 + t;
            int lb = phys ^ ((phys >> 3) & 7);
            int row = lb >> 3, cb = lb & 7;
            int ldsoff = (c * 256 + w * 64) * 8;
            async_ld16(A  + (am0 + row) * 1024 + k0 + cb * 8, (void*)(As + ldsoff));
            async_ld16(BT + (bn0 + row) * 1024 + k0 + cb * 8, (void*)(Bs + ldsoff));
        }
        __syncthreads();
        bf16x8 af[4][2], bfv[4][2];
        #pragma unroll
        for (int mi = 0; mi < 4; ++mi)
            #pragma unroll
            for (int ks = 0; ks < 2; ++ks)
                af[mi][ks] = *(const bf16x8*)(As + swz(wr + mi * 16 + lr, ks * 32 + lg * 8));
        #pragma unroll
        for (int ni = 0; ni < 4; ++ni)
            #pragma unroll
            for (int ks = 0; ks < 2; ++ks)
                bfv[ni][ks] = *(const bf16x8*)(Bs + swz(wc + ni * 16 + lr, ks * 32 + lg * 8));
        #pragma unroll
        for (int mi = 0; mi < 4; ++mi)
            #pragma unroll
            for (int ni = 0; ni < 4; ++ni) {
                acc[mi][ni] = mfma16(af[mi][0], bfv[ni][0], acc[mi][ni]);
                acc[mi][ni] = mfma16(af[mi][1], bfv[ni][1], acc[mi][ni]);
            }
    }

    #pragma unroll
    for (int mi = 0; mi < 4; ++mi)
        #pragma unroll
        for (int ni = 0; ni < 4; ++ni)
            #pragma unroll
            for (int j = 0; j < 4; ++j) {
                size_t gm = am0 + wr + mi * 16 + lg * 4 + j;
                size_t gn = bn0 + wc + ni * 16 + lr;
                float v = acc[mi][ni][j];
                if (MODE == 0) {
                    int which = (int)(gn >> 10);
                    int h = (int)((gn >> 6) & 15);
                    int d = (int)(gn & 63);
                    int bb = (int)(gm >> 11);
                    int l = (int)(gm & 2047);
                    // fold 0.125 * log2(e) into Q so attention works in exp2 domain
                    if (which == 0) v *= 0.18033688011112042f;
                    bf16* dst = (bf16*)C + (size_t)which * ((size_t)BH_ * L_ * HD_);
                    dst[((size_t)(bb * H_ + h) * L_ + l) * HD_ + d] = __float2bfloat16(v);
                } else {
                    ((float*)C)[gm * 1024 + gn] = v;
                }
            }
}

// ---------------------------------------------------------------- V transpose per head
__global__ __launch_bounds__(256) void k_transpose_v(const bf16* __restrict__ Vb, bf16* __restrict__ VTb) {
    __shared__ __align__(16) short tile[64][80];
    const int bh = blockIdx.y;
    const int l0 = blockIdx.x * 64;
    const int t = threadIdx.x;
    const int rr = t >> 2, cc = (t & 3) * 16;
    const short* src = (const short*)(Vb + ((size_t)bh * L_ + l0 + rr) * HD_ + cc);
    *(bf16x8*)&tile[rr][cc]     = *(const bf16x8*)src;
    *(bf16x8*)&tile[rr][cc + 8] = *(const bf16x8*)(src + 8);
    __syncthreads();
    bf16x8 v0, v1;
    #pragma unroll
    for (int i = 0; i < 8; ++i) v0[i] = tile[cc + i][rr];
    #pragma unroll
    for (int i = 0; i < 8; ++i) v1[i] = tile[cc + 8 + i][rr];
    short* dst = (short*)(VTb + ((size_t)bh * HD_ + rr) * L_ + l0 + cc);
    *(bf16x8*)dst       = v0;
    *(bf16x8*)(dst + 8) = v1;
}

// ---------------------------------------------------------------- fused attention
// grid (L/64, H). Step s = (kv-tile it, batch bi=s&1); K/V buffers alternate by batch,
// PE double-buffered per tile. Counted vmcnt(8) pipeline — never drains in the loop.
__global__ __launch_bounds__(256) void k_attn(const bf16* __restrict__ Qb, const bf16* __restrict__ Kb,
                                              const bf16* __restrict__ VTb, const float* __restrict__ PE,
                                              bf16* __restrict__ Ob) {
    __shared__ __align__(16) bf16 Ks[2][64 * 64];
    __shared__ __align__(16) bf16 Vs[2][64 * 64];
    __shared__ __align__(16) float PEs[2][64 * 64];
    __shared__ __align__(16) bf16 Ps[64 * 64];
    const int h = blockIdx.y;
    const int q0 = blockIdx.x * 64;
    const int t = threadIdx.x, w = t >> 6, lane = t & 63;
    const int lr = lane & 15, lg = lane >> 4;

    // Q fragments (pre-scaled by 0.125*log2e at projection), held for whole kernel
    bf16x8 qf[2][2];
    #pragma unroll
    for (int bi = 0; bi < 2; ++bi) {
        const bf16* qsrc = Qb + (((size_t)(bi * H_ + h)) * L_ + q0 + w * 16 + lr) * HD_ + lg * 8;
        qf[bi][0] = *(const bf16x8*)qsrc;
        qf[bi][1] = *(const bf16x8*)(qsrc + 32);
    }

    // ---- staging constants (per-thread global offsets, wave-uniform LDS bases) ----
    int kgoff[2], vgoff[2], kvlds[2];
    #pragma unroll
    for (int c = 0; c < 2; ++c) {
        int phys = c * 256 + t;
        int lb = phys ^ ((phys >> 3) & 7);
        kgoff[c] = (lb >> 3) * HD_ + (lb & 7) * 8;
        vgoff[c] = (lb >> 3) * L_  + (lb & 7) * 8;
        kvlds[c] = (c * 256 + w * 64) * 8;
    }
    int pegoff[4], pelds[4];
    #pragma unroll
    for (int c = 0; c < 4; ++c) {
        int phys = c * 256 + t;
        int row = phys >> 4, c16 = (phys & 15) ^ (row & 15);
        pegoff[c] = row * L_ + c16 * 4;           // f32 elements
        pelds[c]  = (c * 256 + w * 64) * 4;       // f32 elements
    }
    // ---- LDS read offsets ----
    int kro[4][2];
    #pragma unroll
    for (int x = 0; x < 4; ++x)
        #pragma unroll
        for (int ks = 0; ks < 2; ++ks)
            kro[x][ks] = swz(x * 16 + lr, ks * 32 + lg * 8);
    int per[4][4];
    #pragma unroll
    for (int jj = 0; jj < 4; ++jj)
        #pragma unroll
        for (int ni = 0; ni < 4; ++ni) {
            int row = w * 16 + lg * 4 + jj, col = ni * 16 + lr;
            per[jj][ni] = (row * 16 + ((col >> 2) ^ (row & 15))) * 4 + (col & 3);
        }
    int psw[4][4];
    #pragma unroll
    for (int jj = 0; jj < 4; ++jj)
        #pragma unroll
        for (int ni = 0; ni < 4; ++ni)
            psw[jj][ni] = swz(w * 16 + lg * 4 + jj, ni * 16 + lr);
    int psr[2];
    #pragma unroll
    for (int ks = 0; ks < 2; ++ks)
        psr[ks] = swz(w * 16 + lr, ks * 32 + lg * 8);

    const bf16* kb0 = Kb  + ((size_t)(0 * H_ + h)) * L_ * HD_;
    const bf16* kb1 = Kb  + ((size_t)(1 * H_ + h)) * L_ * HD_;
    const bf16* vb0 = VTb + ((size_t)(0 * H_ + h)) * HD_ * L_;
    const bf16* vb1 = VTb + ((size_t)(1 * H_ + h)) * HD_ * L_;
    const float* peb = PE + ((size_t)h * L_ + q0) * L_;

    // ---- prologue: stage (tile0, batch0) + PE(0) ----
    #pragma unroll
    for (int c = 0; c < 2; ++c) {
        async_ld16(kb0 + kgoff[c], (void*)(&Ks[0][0] + kvlds[c]));
        async_ld16(vb0 + vgoff[c], (void*)(&Vs[0][0] + kvlds[c]));
    }
    #pragma unroll
    for (int c = 0; c < 4; ++c)
        async_ld16(peb + pegoff[c], (void*)(&PEs[0][0] + pelds[c]));

    float mrun[2][4], lpart[2][4];
    f32x4 o[2][4] = {};
    #pragma unroll
    for (int bi = 0; bi < 2; ++bi)
        #pragma unroll
        for (int j = 0; j < 4; ++j) { mrun[bi][j] = -3e38f; lpart[bi][j] = 0.f; }

#define COMPUTE(BI) {                                                                   \
    const bf16* ksb = &Ks[BI][0]; const bf16* vsb = &Vs[BI][0];                         \
    const float* pel = &PEs[it & 1][0];                                                 \
    float pev[4][4];                                                                    \
    _Pragma("unroll") for (int jj = 0; jj < 4; ++jj)                                    \
        _Pragma("unroll") for (int ni = 0; ni < 4; ++ni)                                \
            pev[jj][ni] = pel[per[jj][ni]];                                             \
    f32x4 sv[4];                                                                        \
    _Pragma("unroll") for (int ni = 0; ni < 4; ++ni) {                                  \
        f32x4 z = {0.f, 0.f, 0.f, 0.f};                                                 \
        z = mfma16(qf[BI][0], *(const bf16x8*)(ksb + kro[ni][0]), z);                   \
        z = mfma16(qf[BI][1], *(const bf16x8*)(ksb + kro[ni][1]), z);                   \
        sv[ni] = z; }                                                                   \
    _Pragma("unroll") for (int jj = 0; jj < 4; ++jj) {                                  \
        float v0 = fmaf(pev[jj][0], L2E, sv[0][jj]);                                    \
        float v1 = fmaf(pev[jj][1], L2E, sv[1][jj]);                                    \
        float v2 = fmaf(pev[jj][2], L2E, sv[2][jj]);                                    \
        float v3 = fmaf(pev[jj][3], L2E, sv[3][jj]);                                    \
        float vm = fmaxf(fmaxf(v0, v1), fmaxf(v2, v3));                                 \
        vm = fmaxf(vm, __shfl_xor(vm, 1, 16));                                          \
        vm = fmaxf(vm, __shfl_xor(vm, 2, 16));                                          \
        vm = fmaxf(vm, __shfl_xor(vm, 4, 16));                                          \
        vm = fmaxf(vm, __shfl_xor(vm, 8, 16));                                          \
        float mold = mrun[BI][jj];                                                      \
        float mnew = fmaxf(mold, vm);                                                   \
        float scl = __builtin_amdgcn_exp2f(mold - mnew);                                \
        mrun[BI][jj] = mnew;                                                            \
        float p0 = __builtin_amdgcn_exp2f(v0 - mnew);                                   \
        float p1 = __builtin_amdgcn_exp2f(v1 - mnew);                                   \
        float p2 = __builtin_amdgcn_exp2f(v2 - mnew);                                   \
        float p3 = __builtin_amdgcn_exp2f(v3 - mnew);                                   \
        lpart[BI][jj] = lpart[BI][jj] * scl + ((p0 + p1) + (p2 + p3));                  \
        Ps[psw[jj][0]] = __float2bfloat16(p0);                                          \
        Ps[psw[jj][1]] = __float2bfloat16(p1);                                          \
        Ps[psw[jj][2]] = __float2bfloat16(p2);                                          \
        Ps[psw[jj][3]] = __float2bfloat16(p3);                                          \
        o[BI][0][jj] *= scl; o[BI][1][jj] *= scl;                                       \
        o[BI][2][jj] *= scl; o[BI][3][jj] *= scl; }                                     \
    _Pragma("unroll") for (int ks = 0; ks < 2; ++ks) {                                  \
        bf16x8 pa = *(const bf16x8*)(Ps + psr[ks]);                                     \
        _Pragma("unroll") for (int di = 0; di < 4; ++di)                                \
            o[BI][di] = mfma16(pa, *(const bf16x8*)(vsb + kro[di][ks]), o[BI][di]); }   \
}

    for (int it = 0; it < 32; ++it) {
        const int itn = (it < 31) ? it + 1 : 31;
        // ---------- step bi=0: prefetch (tile it, batch1) + PE(it+1) ----------
        __builtin_amdgcn_s_barrier();
        #pragma unroll
        for (int c = 0; c < 2; ++c) {
            async_ld16(kb1 + (size_t)it * 64 * HD_ + kgoff[c], (void*)(&Ks[1][0] + kvlds[c]));
            async_ld16(vb1 + it * 64 + vgoff[c],               (void*)(&Vs[1][0] + kvlds[c]));
        }
        {
            float* ped = ((it + 1) & 1) ? &PEs[1][0] : &PEs[0][0];
            #pragma unroll
            for (int c = 0; c < 4; ++c)
                async_ld16(peb + itn * 64 + pegoff[c], (void*)(ped + pelds[c]));
        }
        asm volatile("s_waitcnt vmcnt(8)" ::: "memory");
        __builtin_amdgcn_s_barrier();
        COMPUTE(0)
        // ---------- step bi=1: prefetch (tile it+1, batch0) ----------
        __builtin_amdgcn_s_barrier();
        #pragma unroll
        for (int c = 0; c < 2; ++c) {
            async_ld16(kb0 + (size_t)itn * 64 * HD_ + kgoff[c], (void*)(&Ks[0][0] + kvlds[c]));
            async_ld16(vb0 + itn * 64 + vgoff[c],               (void*)(&Vs[0][0] + kvlds[c]));
        }
        asm volatile("s_waitcnt vmcnt(8)" ::: "memory");
        __builtin_amdgcn_s_barrier();
        COMPUTE(1)
    }
#undef COMPUTE

    // ---- epilogue: deferred l reduction, normalize, store ----
    #pragma unroll
    for (int bi = 0; bi < 2; ++bi)
        #pragma unroll
        for (int jj = 0; jj < 4; ++jj) {
            float ls = lpart[bi][jj];
            ls += __shfl_xor(ls, 1, 16);
            ls += __shfl_xor(ls, 2, 16);
            ls += __shfl_xor(ls, 4, 16);
            ls += __shfl_xor(ls, 8, 16);
            float inv = __builtin_amdgcn_rcpf(ls);
            #pragma unroll
            for (int di = 0; di < 4; ++di) {
                float v = o[bi][di][jj] * inv;
                size_t gq = q0 + w * 16 + lg * 4 + jj;
                Ob[((size_t)bi * L_ + gq) * D_ + h * HD_ + di * 16 + lr] = __float2bfloat16(v);
            }
        }
    // drain dangling LDS-DMA before the block retires (tail prefetches)
    asm volatile("s_waitcnt vmcnt(0)" ::: "memory");
}

// ---------------------------------------------------------------- launch
extern "C" void kernel_launch(void* const* d_in, const int* in_sizes, int n_in,
                              void* d_out, int out_size, void* d_ws, size_t ws_size,
                              hipStream_t stream) {
    const float* x  = (const float*)d_in[0];
    const float* pe = (const float*)d_in[1];
    const float* Wq = (const float*)d_in[2];
    const float* Wk = (const float*)d_in[3];
    const float* Wv = (const float*)d_in[4];
    const float* Wo = (const float*)d_in[5];
    float* out = (float*)d_out;

    const size_t MD = (size_t)4096 * 1024;
    const size_t HS = (size_t)BH_ * L_ * HD_;

    bf16* Xb  = (bf16*)d_ws;        // x in bf16            [4096][1024]
    bf16* WT  = Xb + MD;            // WqT|WkT|WvT|WoT      [4096][1024]
    bf16* Qb  = WT + MD;            // [bh][L][64]
    bf16* Kb  = Qb + HS;
    bf16* Vb  = Kb + HS;
    bf16* VTb = Vb + HS;            // [bh][64][L]
    bf16* Ob  = VTb + HS;           // attention out        [4096][1024]

    k_cast_x<<<2048, 256, 0, stream>>>(x, Xb, 4096 * 1024 / 8);
    k_cast_wT<<<dim3(16, 16, 4), 256, 0, stream>>>(Wq, Wk, Wv, Wo, WT);
    k_gemm<0><<<dim3(24, 32), 256, 0, stream>>>(Xb, WT, (void*)Qb);          // QKV, N=3072
    k_transpose_v<<<dim3(32, 32), 256, 0, stream>>>(Vb, VTb);
    k_attn<<<dim3(32, 16), 256, 0, stream>>>(Qb, Kb, VTb, pe, Ob);
    k_gemm<1><<<dim3(8, 32), 256, 0, stream>>>(Ob, WT + (size_t)3072 * 1024, (void*)out); // out-proj
}